// Round 1
// baseline (9.468 us; speedup 1.0000x reference)
//
#include <hip/hip_runtime.h>

// PointerNet_30949534335591
//
// The reference's output is ptrs.T where ptr = argmax(logits, axis=1) and
// logits has shape [B, 1] (ptr_W is (1, H)). argmax over a length-1 axis is
// identically 0 for every batch row and every decoder step, independent of
// all inputs (even NaNs: argmax of a single element is index 0). The
// encoder/decoder LSTM states never reach the output. Therefore the exact,
// faithful output is a [B, S] array of zeros (B*S = out_size elements).
//
// int32 zero and float32 zero are bit-identical (0x00000000), so writing
// 4-byte zeros is correct regardless of how the harness types the output.
//
// d_out is poisoned to 0xAA before timing, so we must (and do) write the
// zeros on every call. Deterministic, no state.

__global__ void ptrnet_zero_out(int* __restrict__ out, int n) {
    int idx = blockIdx.x * blockDim.x + threadIdx.x;
    int i4 = idx << 2;                       // 16 B per thread (coalesced int4)
    if (i4 + 3 < n) {
        *reinterpret_cast<int4*>(out + i4) = make_int4(0, 0, 0, 0);
    } else {
        for (int i = i4; i < n; ++i) out[i] = 0;  // tail (unused: n % 4 == 0)
    }
}

extern "C" void kernel_launch(void* const* d_in, const int* in_sizes, int n_in,
                              void* d_out, int out_size, void* d_ws, size_t ws_size,
                              hipStream_t stream) {
    (void)d_in; (void)in_sizes; (void)n_in; (void)d_ws; (void)ws_size;
    // out_size = B*S = 256*512 = 131072 elements (4 B each) = 512 KiB.
    const int threads = 256;
    const int n4 = (out_size + 3) / 4;               // elements-of-4 per thread
    const int blocks = (n4 + threads - 1) / threads; // 128 blocks at out_size=131072
    ptrnet_zero_out<<<blocks, threads, 0, stream>>>((int*)d_out, out_size);
}